// Round 7
// baseline (106.105 us; speedup 1.0000x reference)
//
#include <hip/hip_runtime.h>

#define N 4096
#define M 1024
#define D 64
#define MT 16                             // m-values per thread
#define SPLITS 16                         // N-chunks
#define ROWS_PER_BLOCK (N / SPLITS)       // 256
#define ROWS_PER_WAVE  (ROWS_PER_BLOCK/4) // 64
#define SITES (M * D)                     // 65536
#define NGROUPS 64
#define GSTRIDE 16                        // ints between group counters (64 B)
#define NWORK 64                          // worker blocks for the fused tail
#define CTR_OFF (4u << 20)                // ctrs live after the 4 MB pout region

// Register-only 3-input min (v_min3_f32), minnum semantics = fminf twice.
__device__ __forceinline__ float min3f(float a, float b, float c) {
    float d;
    asm("v_min3_f32 %0, %1, %2, %3" : "=v"(d) : "v"(a), "v"(b), "v"(c));
    return d;
}

// Single fused kernel. Phase 1 (all 1024 blocks): R6's k_minpart verbatim,
// except pout is published with agent-scope atomic stores (cross-XCD safe
// within one dispatch). Arrival: two-level counters (64 groups x 16) -> no
// serial atomic burst. Phase 2 (blocks 0..63): spin-sleep on root, then each
// reduces a FIXED 1024-site slice; last worker does the 64-parallel-read +
// fixed-order-tree finish. Deterministic; deadlock-free at any occupancy.
__global__ __launch_bounds__(256) void k_fused(const float* __restrict__ z,
                                               const float* __restrict__ e,
                                               const int* __restrict__ idx,
                                               float* __restrict__ pout,
                                               float* __restrict__ out,
                                               int* __restrict__ ctrs) {
    const int bid = blockIdx.x;

    // fused elementwise outputs: 256 elements per block
    {
        const int i = bid * 256 + (int)threadIdx.x;
        const float zv = z[i];
        const int row = i >> 6, dd = i & 63;
        out[1 + i] = (dd < idx[row]) ? zv : 0.0f;   // z_masked
        out[1 + N * D + i] = zv;                    // z_copy
    }

    const int mt   = bid & 63;    // m-tile
    const int s    = bid >> 6;    // split
    const int lane = threadIdx.x & 63;
    const int w    = threadIdx.x >> 6;
    const int m0   = mt * MT;

    float n2e[MT];
#pragma unroll
    for (int j = 0; j < MT; ++j) n2e[j] = -2.0f * e[(m0 + j) * D + lane];

    float acc[MT];
#pragma unroll
    for (int j = 0; j < MT; ++j) acc[j] = 3.4e38f;

    const float* zp = z + (s * ROWS_PER_BLOCK + w * ROWS_PER_WAVE) * D + lane;
#pragma unroll 4
    for (int r4 = 0; r4 < ROWS_PER_WAVE / 4; ++r4) {   // 16 batches of 4 rows
        const float za = zp[(4 * r4 + 0) * D];
        const float zb = zp[(4 * r4 + 1) * D];
        const float zc = zp[(4 * r4 + 2) * D];
        const float zd = zp[(4 * r4 + 3) * D];
        const float za2 = za * za, zb2 = zb * zb;
        const float zc2 = zc * zc, zd2 = zd * zd;
#pragma unroll
        for (int j = 0; j < MT; ++j) {
            const float t1 = fmaf(n2e[j], za, za2);
            const float t2 = fmaf(n2e[j], zb, zb2);
            const float t3 = fmaf(n2e[j], zc, zc2);
            const float t4 = fmaf(n2e[j], zd, zd2);
            acc[j] = min3f(acc[j], min3f(t1, t2, t3), t4);
        }
    }

    __shared__ float lds[4][MT * 64];
#pragma unroll
    for (int j = 0; j < MT; ++j) lds[w][j * 64 + lane] = acc[j];
    __syncthreads();
    for (int p = threadIdx.x; p < MT * 64; p += 256) {
        const float v = fminf(fminf(lds[0][p], lds[1][p]),
                              fminf(lds[2][p], lds[3][p]));
        __hip_atomic_store(&pout[s * SITES + m0 * 64 + p], v,
                           __ATOMIC_RELAXED, __HIP_MEMORY_SCOPE_AGENT);
    }
    __threadfence();
    __syncthreads();   // all lanes' pout stores issued+fenced before arrival
    if (threadIdx.x == 0) {
        const int old = __hip_atomic_fetch_add(&ctrs[(bid & 63) * GSTRIDE], 1,
                                               __ATOMIC_ACQ_REL, __HIP_MEMORY_SCOPE_AGENT);
        if (old == SPLITS - 1)   // 16th arrival closes the group
            __hip_atomic_fetch_add(&ctrs[1024], 1,
                                   __ATOMIC_ACQ_REL, __HIP_MEMORY_SCOPE_AGENT);
    }
    if (bid >= NWORK) return;   // non-workers free their CU slots

    // ---- phase 2: worker tail ----
    if (threadIdx.x == 0) {
        while (__hip_atomic_load(&ctrs[1024], __ATOMIC_ACQUIRE,
                                 __HIP_MEMORY_SCOPE_AGENT) < NGROUPS)
            __builtin_amdgcn_s_sleep(8);
    }
    __syncthreads();
    __threadfence();

    float local = 0.0f;
#pragma unroll
    for (int k = 0; k < 4; ++k) {
        const int site = bid * 1024 + k * 256 + (int)threadIdx.x;  // coalesced
        float v = 3.4e38f;
#pragma unroll
        for (int si = 0; si < SPLITS; ++si)
            v = fminf(v, __hip_atomic_load(&pout[si * SITES + site],
                                           __ATOMIC_RELAXED, __HIP_MEMORY_SCOPE_AGENT));
        const float ev = e[site];
        local += v + ev * ev;
    }
#pragma unroll
    for (int off = 32; off > 0; off >>= 1)
        local += __shfl_down(local, off, 64);
    __shared__ float wsum[4];
    __shared__ int fin;
    if (lane == 0) wsum[w] = local;
    __syncthreads();
    float* slice = (float*)&ctrs[1056];
    if (threadIdx.x == 0) {
        atomicExch(&slice[bid], (wsum[0] + wsum[1]) + (wsum[2] + wsum[3]));
        __threadfence();
        fin = (__hip_atomic_fetch_add(&ctrs[1040], 1, __ATOMIC_ACQ_REL,
                                      __HIP_MEMORY_SCOPE_AGENT) == NWORK - 1);
    }
    __syncthreads();
    if (fin && threadIdx.x < 64) {
        __threadfence();
        float v = atomicAdd(&slice[threadIdx.x], 0.0f);  // 64 parallel reads
#pragma unroll
        for (int off = 32; off > 0; off >>= 1)
            v += __shfl_down(v, off, 64);
        if (threadIdx.x == 0) out[0] = v * (1.0f / SITES);
    }
}

extern "C" void kernel_launch(void* const* d_in, const int* in_sizes, int n_in,
                              void* d_out, int out_size, void* d_ws, size_t ws_size,
                              hipStream_t stream) {
    const float* z   = (const float*)d_in[0];
    const float* e   = (const float*)d_in[1];
    const int*   idx = (const int*)d_in[2];
    float* out  = (float*)d_out;
    float* pout = (float*)d_ws;                         // 4 MB partial mins
    int*   ctrs = (int*)((char*)d_ws + CTR_OFF);        // counters + slice sums

    hipMemsetAsync((char*)d_ws + CTR_OFF, 0, 8192, stream);
    k_fused<<<64 * SPLITS, 256, 0, stream>>>(z, e, idx, pout, out, ctrs);
}

// Round 8
// 42.122 us; speedup vs baseline: 2.5190x; 2.5190x over previous
//
#include <hip/hip_runtime.h>

#define N 4096
#define M 1024
#define D 64
#define B 1024            // buckets per column
#define NZ (N * D)        // 262144
#define COLBLKS 64
#define MASKBLKS 128
#define BIGF 3.4e38f

// K1: blocks 0..63: exact 1-D nearest-neighbor per column via bucket sort in
// LDS + outward scan (stop rule has one-bucket slack -> provably includes the
// true argmin; fl monotonicity makes the result bit-exact vs reference).
// Blocks 64..191: z_masked / z_copy elementwise outputs.
__global__ __launch_bounds__(256) void k_nn(const float* __restrict__ z,
                                            const float* __restrict__ e,
                                            const int* __restrict__ idx,
                                            float* __restrict__ colsum,
                                            float* __restrict__ out) {
    const int bid = blockIdx.x;
    const int t   = (int)threadIdx.x;

    if (bid >= COLBLKS) {   // ---- mask/copy blocks ----
        const int base = (bid - COLBLKS) * 2048;
#pragma unroll
        for (int k = 0; k < 8; ++k) {
            const int i = base + k * 256 + t;
            const float zv = z[i];
            const int row = i >> 6, dd = i & 63;
            out[1 + i] = (dd < idx[row]) ? zv : 0.0f;   // z_masked
            out[1 + NZ + i] = zv;                       // z_copy
        }
        return;
    }

    // ---- column blocks ----
    const int d = bid;
    __shared__ float zs[N];            // bucket-sorted column (16 KB)
    __shared__ int   start[B + 1];     // bucket start offsets (used as cnt first)
    __shared__ int   ofs[B];           // bump allocators
    __shared__ int   scan0[256], scan1[256];
    __shared__ float redf[4];
    __shared__ float sm_min, sm_max;

    // pass A: load 16 column values/thread, block min/max
    float v[16];
    float vmin = BIGF, vmax = -BIGF;
#pragma unroll
    for (int k = 0; k < 16; ++k) {
        v[k] = z[(t + k * 256) * D + d];
        vmin = fminf(vmin, v[k]);
        vmax = fmaxf(vmax, v[k]);
    }
#pragma unroll
    for (int off = 32; off > 0; off >>= 1) {
        vmin = fminf(vmin, __shfl_down(vmin, off, 64));
        vmax = fmaxf(vmax, __shfl_down(vmax, off, 64));
    }
    const int lane = t & 63, w4 = t >> 6;
    __shared__ float wmin[4], wmax[4];
    if (lane == 0) { wmin[w4] = vmin; wmax[w4] = vmax; }
    for (int i = t; i < B + 1; i += 256) start[i] = 0;
    __syncthreads();
    if (t == 0) {
        sm_min = fminf(fminf(wmin[0], wmin[1]), fminf(wmin[2], wmin[3]));
        sm_max = fmaxf(fmaxf(wmax[0], wmax[1]), fmaxf(wmax[2], wmax[3]));
    }
    __syncthreads();
    const float zmin = sm_min;
    const float w    = fmaxf((sm_max - zmin) * (1.0f / B), 1e-12f);
    const float invw = 1.0f / w;

    // histogram
#pragma unroll
    for (int k = 0; k < 16; ++k) {
        int b = (int)((v[k] - zmin) * invw);
        b = b < 0 ? 0 : (b > B - 1 ? B - 1 : b);
        atomicAdd(&start[b], 1);
    }
    __syncthreads();

    // prefix sum: each thread owns 4 buckets; Hillis-Steele over 256 thread sums
    const int c0 = start[4 * t], c1 = start[4 * t + 1];
    const int c2 = start[4 * t + 2], c3 = start[4 * t + 3];
    const int tsum = c0 + c1 + c2 + c3;
    scan0[t] = tsum;
    __syncthreads();
    int val = tsum;
    int* src = scan0; int* dst = scan1;
    for (int dd = 1; dd < 256; dd <<= 1) {
        const int add = (t >= dd) ? src[t - dd] : 0;
        val += add;
        dst[t] = val;
        __syncthreads();
        int* tmp = src; src = dst; dst = tmp;
    }
    const int excl = val - tsum;
    const int o0 = excl, o1 = o0 + c0, o2 = o1 + c1, o3 = o2 + c2;
    start[4 * t] = o0; start[4 * t + 1] = o1;
    start[4 * t + 2] = o2; start[4 * t + 3] = o3;
    ofs[4 * t] = o0; ofs[4 * t + 1] = o1; ofs[4 * t + 2] = o2; ofs[4 * t + 3] = o3;
    if (t == 255) start[B] = o3 + c3;   // = 4096
    __syncthreads();

    // pass B: scatter into bucket-sorted order
#pragma unroll
    for (int k = 0; k < 16; ++k) {
        int b = (int)((v[k] - zmin) * invw);
        b = b < 0 ? 0 : (b > B - 1 ? B - 1 : b);
        const int p = atomicAdd(&ofs[b], 1);
        zs[p] = v[k];
    }
    __syncthreads();

    // query phase: 4 queries/thread, outward bucket scan with w-slack stop
    float acc = 0.0f;
#pragma unroll
    for (int k = 0; k < 4; ++k) {
        const int m = t + k * 256;
        const float q = e[m * D + d];
        int bq = (int)((q - zmin) * invw);
        bq = bq < 0 ? 0 : (bq > B - 1 ? B - 1 : bq);
        float best = BIGF;
        for (int i = start[bq]; i < start[bq + 1]; ++i)
            best = fminf(best, fabsf(zs[i] - q));
        int lo = bq, hi = bq;
        for (;;) {
            const float dL = (lo > 0)     ? (q - fmaf((float)lo, w, zmin))       : BIGF;
            const float dR = (hi < B - 1) ? (fmaf((float)(hi + 1), w, zmin) - q) : BIGF;
            const bool doneL = (best + w <= dL) || (lo == 0);
            const bool doneR = (best + w <= dR) || (hi == B - 1);
            if (doneL && doneR) break;
            if (!doneL) {
                --lo;
                for (int i = start[lo]; i < start[lo + 1]; ++i)
                    best = fminf(best, fabsf(zs[i] - q));
            }
            if (!doneR) {
                ++hi;
                for (int i = start[hi]; i < start[hi + 1]; ++i)
                    best = fminf(best, fabsf(zs[i] - q));
            }
        }
        acc += best * best;   // fl(best^2) == reference's min of fl(fl(z-q)^2)
    }

    // deterministic block sum -> colsum[d]
#pragma unroll
    for (int off = 32; off > 0; off >>= 1)
        acc += __shfl_down(acc, off, 64);
    if (lane == 0) redf[w4] = acc;
    __syncthreads();
    if (t == 0)
        colsum[d] = (redf[0] + redf[1]) + (redf[2] + redf[3]);
}

// K2: tiny deterministic finish — 64 column partials -> scalar.
__global__ void k_final(const float* __restrict__ colsum, float* __restrict__ out) {
    float v = colsum[threadIdx.x];
#pragma unroll
    for (int off = 32; off > 0; off >>= 1)
        v += __shfl_down(v, off, 64);
    if (threadIdx.x == 0) out[0] = v * (1.0f / (M * D));
}

extern "C" void kernel_launch(void* const* d_in, const int* in_sizes, int n_in,
                              void* d_out, int out_size, void* d_ws, size_t ws_size,
                              hipStream_t stream) {
    const float* z   = (const float*)d_in[0];
    const float* e   = (const float*)d_in[1];
    const int*   idx = (const int*)d_in[2];
    float* out    = (float*)d_out;
    float* colsum = (float*)d_ws;   // 64 floats, fully rewritten every call

    k_nn<<<COLBLKS + MASKBLKS, 256, 0, stream>>>(z, e, idx, colsum, out);
    k_final<<<1, 64, 0, stream>>>(colsum, out);
}

// Round 9
// 23.053 us; speedup vs baseline: 4.6026x; 1.8271x over previous
//
#include <hip/hip_runtime.h>

#define N 4096
#define M 1024
#define D 64
#define MT 16                             // m-values per thread
#define SPLITS 16                         // N-chunks (champion config)
#define ROWS_PER_BLOCK (N / SPLITS)       // 256
#define ROWS_PER_WAVE  (ROWS_PER_BLOCK/4) // 64
#define NB (ROWS_PER_WAVE / 4)            // 16 four-row batches
#define SITES (M * D)                     // 65536
#define K2_BLOCKS 64

// Register-only 3-input min (v_min3_f32), minnum semantics = fminf twice.
__device__ __forceinline__ float min3f(float a, float b, float c) {
    float d;
    asm("v_min3_f32 %0, %1, %2, %3" : "=v"(d) : "v"(a), "v"(b), "v"(c));
    return d;
}

// K1: partial min over an N-chunk for a 16-m tile, z_masked/z_copy fused.
// grid = 64 m-tiles * 16 splits = 1024 blocks, 256 threads, lane = d.
// min_n (z-e)^2 = min_n (z^2-2ez) + e^2.
// NEW: explicit distance-1 software pipeline — batch r+1's 4 z-loads are
// issued BEFORE batch r's 100-op compute, so ~200cyc L2 latency hides under
// ~200cyc of VALU instead of serializing with it.
__global__ __launch_bounds__(256) void k_minpart(const float* __restrict__ z,
                                                 const float* __restrict__ e,
                                                 const int* __restrict__ idx,
                                                 float* __restrict__ pout,
                                                 float* __restrict__ out,
                                                 int* __restrict__ counter) {
    const int bid = blockIdx.x;
    if (bid == 0 && threadIdx.x == 0) *counter = 0;   // reset for K2, every call

    // fused elementwise outputs: 256 elements per block
    {
        const int i = bid * 256 + (int)threadIdx.x;
        const float zv = z[i];
        const int row = i >> 6, dd = i & 63;
        out[1 + i] = (dd < idx[row]) ? zv : 0.0f;   // z_masked
        out[1 + N * D + i] = zv;                    // z_copy
    }

    const int mt   = bid & 63;    // m-tile
    const int s    = bid >> 6;    // split
    const int lane = threadIdx.x & 63;
    const int w    = threadIdx.x >> 6;
    const int m0   = mt * MT;

    float n2e[MT];
#pragma unroll
    for (int j = 0; j < MT; ++j) n2e[j] = -2.0f * e[(m0 + j) * D + lane];

    float acc[MT];
#pragma unroll
    for (int j = 0; j < MT; ++j) acc[j] = 3.4e38f;

    const float* zp = z + (s * ROWS_PER_BLOCK + w * ROWS_PER_WAVE) * D + lane;

    // pipeline prologue: batch 0 loads
    float za = zp[0 * D], zb = zp[1 * D], zc = zp[2 * D], zd = zp[3 * D];

#pragma unroll
    for (int r4 = 0; r4 < NB - 1; ++r4) {   // 15 pipelined batches
        // issue next batch's loads first (independent of current compute)
        const float na = zp[(4 * r4 + 4) * D];
        const float nb = zp[(4 * r4 + 5) * D];
        const float nc = zp[(4 * r4 + 6) * D];
        const float nd = zp[(4 * r4 + 7) * D];
        const float za2 = za * za, zb2 = zb * zb;
        const float zc2 = zc * zc, zd2 = zd * zd;
#pragma unroll
        for (int j = 0; j < MT; ++j) {
            const float t1 = fmaf(n2e[j], za, za2);
            const float t2 = fmaf(n2e[j], zb, zb2);
            const float t3 = fmaf(n2e[j], zc, zc2);
            const float t4 = fmaf(n2e[j], zd, zd2);
            acc[j] = min3f(acc[j], min3f(t1, t2, t3), t4);
        }
        za = na; zb = nb; zc = nc; zd = nd;
    }
    {   // epilogue: last batch, no prefetch
        const float za2 = za * za, zb2 = zb * zb;
        const float zc2 = zc * zc, zd2 = zd * zd;
#pragma unroll
        for (int j = 0; j < MT; ++j) {
            const float t1 = fmaf(n2e[j], za, za2);
            const float t2 = fmaf(n2e[j], zb, zb2);
            const float t3 = fmaf(n2e[j], zc, zc2);
            const float t4 = fmaf(n2e[j], zd, zd2);
            acc[j] = min3f(acc[j], min3f(t1, t2, t3), t4);
        }
    }

    __shared__ float lds[4][MT * 64];
#pragma unroll
    for (int j = 0; j < MT; ++j) lds[w][j * 64 + lane] = acc[j];
    __syncthreads();
    for (int p = threadIdx.x; p < MT * 64; p += 256) {
        const float v = fminf(fminf(lds[0][p], lds[1][p]),
                              fminf(lds[2][p], lds[3][p]));
        pout[s * SITES + m0 * 64 + p] = v;   // coalesced
    }
}

// K2: champion form. min over 16 splits + e^2, sum; 64 blocks, 4 sites/thread;
// deterministic last-block finish: 64 PARALLEL coherent reads + fixed tree.
__global__ __launch_bounds__(256) void k_minsum(const float* __restrict__ pout,
                                                const float* __restrict__ e,
                                                float* __restrict__ bsums,
                                                int* __restrict__ counter,
                                                float* __restrict__ out) {
    const int t = blockIdx.x * 256 + (int)threadIdx.x;  // 16384 threads
    float local = 0.0f;
#pragma unroll
    for (int k = 0; k < 4; ++k) {
        const int site = t + k * 16384;
        float v = 3.4e38f;
#pragma unroll
        for (int si = 0; si < SPLITS; ++si)
            v = fminf(v, pout[si * SITES + site]);
        const float ev = e[site];
        local += v + ev * ev;
    }
#pragma unroll
    for (int off = 32; off > 0; off >>= 1)
        local += __shfl_down(local, off, 64);
    __shared__ float wsum[4];
    __shared__ int is_last;
    const int lane = threadIdx.x & 63, w = threadIdx.x >> 6;
    if (lane == 0) wsum[w] = local;
    __syncthreads();
    if (threadIdx.x == 0) {
        atomicExch(&bsums[blockIdx.x], (wsum[0] + wsum[1]) + (wsum[2] + wsum[3]));
        __threadfence();
        is_last = (atomicAdd(counter, 1) == K2_BLOCKS - 1);
    }
    __syncthreads();
    if (is_last && threadIdx.x < 64) {
        __threadfence();
        float v = atomicAdd(&bsums[threadIdx.x], 0.0f);  // 64 parallel reads
#pragma unroll
        for (int off = 32; off > 0; off >>= 1)
            v += __shfl_down(v, off, 64);
        if (threadIdx.x == 0) out[0] = v * (1.0f / SITES);
    }
}

extern "C" void kernel_launch(void* const* d_in, const int* in_sizes, int n_in,
                              void* d_out, int out_size, void* d_ws, size_t ws_size,
                              hipStream_t stream) {
    const float* z   = (const float*)d_in[0];
    const float* e   = (const float*)d_in[1];
    const int*   idx = (const int*)d_in[2];
    float* out = (float*)d_out;

    float* pout    = (float*)d_ws;                       // 4 MB partials
    float* bsums   = (float*)d_ws + SPLITS * SITES;      // 64 floats
    int*   counter = (int*)(bsums + K2_BLOCKS);

    k_minpart<<<64 * SPLITS, 256, 0, stream>>>(z, e, idx, pout, out, counter);
    k_minsum<<<K2_BLOCKS, 256, 0, stream>>>(pout, e, bsums, counter, out);
}